// Round 17
// baseline (52.507 us; speedup 1.0000x reference)
//
#include <hip/hip_runtime.h>

#define LL 4096
#define THREADS 512
#define KK 8

typedef float v2f __attribute__((ext_vector_type(2)));

// Pad-1-per-16 layout: elem i lives at i + (i>>4). Uniform 4 lanes/bank-pair
// (b64 minimum) for every access pattern here; all FFT pass accesses fold to
// base + compile-time ds-offset immediates.
#define PD(i) ((i) + ((i) >> 4))
#define PERM8(r) ((((r) & 3) << 1) | ((r) >> 2))

__device__ __forceinline__ float sinr(float x) {
    float r; asm("v_sin_f32 %0, %1" : "=v"(r) : "v"(x)); return r;
}
__device__ __forceinline__ float cosr(float x) {
    float r; asm("v_cos_f32 %0, %1" : "=v"(r) : "v"(x)); return r;
}

// ---- VOP3P packed-f32 complex primitives ----
__device__ __forceinline__ v2f padd(v2f a, v2f b) {
    v2f d; asm("v_pk_add_f32 %0, %1, %2" : "=v"(d) : "v"(a), "v"(b)); return d;
}
__device__ __forceinline__ v2f psub(v2f a, v2f b) {
    v2f d; asm("v_pk_add_f32 %0, %1, %2 neg_lo:[0,1] neg_hi:[0,1]" : "=v"(d) : "v"(a), "v"(b)); return d;
}
__device__ __forceinline__ v2f pmul(v2f a, v2f b) {
    v2f d; asm("v_pk_mul_f32 %0, %1, %2" : "=v"(d) : "v"(a), "v"(b)); return d;
}
__device__ __forceinline__ v2f addmi(v2f a, v2f b) {   // a + (-i*b)
    v2f d; asm("v_pk_add_f32 %0, %1, %2 op_sel:[0,1] op_sel_hi:[1,0] neg_hi:[0,1]" : "=v"(d) : "v"(a), "v"(b)); return d;
}
__device__ __forceinline__ v2f submi(v2f a, v2f b) {   // a - (-i*b)
    v2f d; asm("v_pk_add_f32 %0, %1, %2 op_sel:[0,1] op_sel_hi:[1,0] neg_lo:[0,1]" : "=v"(d) : "v"(a), "v"(b)); return d;
}
__device__ __forceinline__ v2f negi(v2f a) {           // -i*a
    v2f d; asm("v_pk_add_f32 %0, %1, 0 op_sel:[1,0] op_sel_hi:[0,0] neg_hi:[1,0]" : "=v"(d) : "v"(a)); return d;
}
__device__ __forceinline__ v2f pfma(v2f a, v2f b, v2f c) {
    v2f d; asm("v_pk_fma_f32 %0, %1, %2, %3" : "=v"(d) : "v"(a), "v"(b), "v"(c)); return d;
}
__device__ __forceinline__ v2f pfms(v2f a, v2f b, v2f c) {
    v2f d; asm("v_pk_fma_f32 %0, %1, %2, %3 neg_lo:[0,0,1] neg_hi:[0,0,1]" : "=v"(d) : "v"(a), "v"(b), "v"(c)); return d;
}
__device__ __forceinline__ v2f cmul(v2f a, v2f b) {
    v2f t2, d;
    asm("v_pk_mul_f32 %0, %1, %2 op_sel:[0,0] op_sel_hi:[0,1]" : "=v"(t2) : "v"(a), "v"(b));
    asm("v_pk_fma_f32 %0, %1, %2, %3 op_sel:[1,1,0] op_sel_hi:[1,0,1] neg_lo:[1,0,0]"
        : "=v"(d) : "v"(a), "v"(b), "v"(t2));
    return d;
}
__device__ __forceinline__ v2f cmulw(v2f z, v2f w) {   // z * conj(w)
    v2f t2, d;
    asm("v_pk_mul_f32 %0, %1, %2 op_sel:[0,0] op_sel_hi:[1,0]" : "=v"(t2) : "v"(z), "v"(w));
    asm("v_pk_fma_f32 %0, %1, %2, %3 op_sel:[1,1,0] op_sel_hi:[0,1,1] neg_hi:[1,0,0]"
        : "=v"(d) : "v"(z), "v"(w), "v"(t2));
    return d;
}
__device__ __forceinline__ v2f unt0(v2f z, v2f y) {
    v2f d; asm("v_pk_add_f32 %0, %1, %2 neg_hi:[0,1]" : "=v"(d) : "v"(z), "v"(y)); return d;
}
__device__ __forceinline__ v2f unt1(v2f z, v2f y) {
    v2f d; asm("v_pk_add_f32 %0, %1, %2 op_sel:[1,1] op_sel_hi:[0,0] neg_hi:[1,0]" : "=v"(d) : "v"(z), "v"(y)); return d;
}

__device__ __forceinline__ void dft4(v2f& a, v2f& b, v2f& c, v2f& d) {
    v2f t0 = padd(a, c), t1 = psub(a, c);
    v2f t2 = padd(b, d), t3 = psub(b, d);
    a = padd(t0, t2); c = psub(t0, t2);
    b = addmi(t1, t3); d = submi(t1, t3);
}

__device__ __forceinline__ void dft8(v2f* v) {
    dft4(v[0], v[2], v[4], v[6]);
    dft4(v[1], v[3], v[5], v[7]);
    const float C2 = 0.70710678118654752f;
    v[3] = cmulw(v[3], (v2f){C2, C2});
    v[5] = negi(v[5]);
    v[7] = cmulw(v[7], (v2f){-C2, C2});
#pragma unroll
    for (int k0 = 0; k0 < 4; ++k0) {
        v2f a = v[2 * k0], b = v[2 * k0 + 1];
        v[2 * k0]     = padd(a, b);
        v[2 * k0 + 1] = psub(a, b);
    }
}

__device__ __forceinline__ void twiddle7w(v2f* v, v2f w1) {
    v2f w2 = cmul(w1, w1);
    v2f w3 = cmul(w2, w1);
    v2f w4 = cmul(w2, w2);
    v2f w5 = cmul(w3, w2);
    v2f w6 = cmul(w3, w3);
    v2f w7 = cmul(w4, w3);
    v[1] = cmulw(v[1], w1);
    v[2] = cmulw(v[2], w2);
    v[3] = cmulw(v[3], w3);
    v[4] = cmulw(v[4], w4);
    v[5] = cmulw(v[5], w5);
    v[6] = cmulw(v[6], w6);
    v[7] = cmulw(v[7], w7);
}

// sparse-inverse state init: 4 packed rotator pairs from selF/selAB
__device__ __forceinline__ void inv_init(v2f* rc, v2f* rp, v2f* tcv, v2f* sgv,
                                         const int* sF, const v2f* sAB,
                                         const v2f* T1, const v2f* T2, int u) {
#pragma unroll
    for (int j = 0; j < 4; ++j) {
        int f0 = sF[2 * j], f1 = sF[2 * j + 1];
        v2f A0 = sAB[2 * j], A1 = sAB[2 * j + 1];
        int m0 = (f0 * u) & 4095, m1 = (f1 * u) & 4095;
        v2f e0 = cmul(T1[m0 >> 6], T2[m0 & 63]);
        v2f e1 = cmul(T1[m1 >> 6], T2[m1 & 63]);
        v2f w0 = cmul(A0, e0);
        v2f w1 = cmul(A1, e1);
        v2f s0 = T1[(f0 & 15) << 2];
        v2f s1 = T1[(f1 & 15) << 2];
        rc[j] = (v2f){w0.x, w1.x};
        rp[j] = (v2f){w0.x * s0.x + w0.y * s0.y, w1.x * s1.x + w1.y * s1.y};
        tcv[j] = (v2f){s0.x + s0.x, s1.x + s1.x};
        sgv[j] = (v2f){(f0 & 1) ? -1.f : 1.f, (f1 & 1) ? -1.f : 1.f};
    }
}

__device__ __forceinline__ void inv_run(v2f* rc, v2f* rp, const v2f* tcv,
                                        const v2f* sgv, float* op, int u) {
#pragma unroll
    for (int q2 = 0; q2 < 8; ++q2) {
        v2f accv = padd(padd(rc[0], rc[1]), padd(rc[2], rc[3]));
        v2f acdv = pfma(rc[0], sgv[0],
                   pfma(rc[1], sgv[1],
                   pfma(rc[2], sgv[2], pmul(rc[3], sgv[3]))));
        op[u + (q2 << 8)] = accv.x + accv.y;
        op[u + (q2 << 8) + 2048] = acdv.x + acdv.y;
#pragma unroll
        for (int j = 0; j < 4; ++j) {
            v2f rn = pfms(tcv[j], rc[j], rp[j]);
            rp[j] = rc[j];
            rc[j] = rn;
        }
    }
}

#define DPP_STEP(CTRL)                                                          \
  {                                                                             \
    int vs_ = __builtin_amdgcn_update_dpp(__float_as_int(bv), __float_as_int(bv), \
                                          CTRL, 0xf, 0xf, false);               \
    int bs_ = __builtin_amdgcn_update_dpp(bb, bb, CTRL, 0xf, 0xf, false);       \
    float vf_ = __int_as_float(vs_);                                            \
    bool tk_ = (vf_ > bv) || (vf_ == bv && bs_ < bb);                           \
    bv = tk_ ? vf_ : bv; bb = tk_ ? bs_ : bb;                                   \
  }
#define DPP_ADD(CTRL)                                                           \
  ps += __int_as_float(__builtin_amdgcn_update_dpp(0, __float_as_int(ps),       \
                                                   CTRL, 0xf, 0xf, true));

#define MOD_DOT(C0)                                                             \
    {                                                                           \
        int mh_ = t >> 8, tt_ = t & 255;                                        \
        const float* tp_ = te + b * 512;                                        \
        const float* wp_ = W + ((C0) + mh_) * 512;                              \
        float ps = tp_[tt_] * wp_[tt_] + tp_[tt_ + 256] * wp_[tt_ + 256];       \
        DPP_ADD(0x111) DPP_ADD(0x112) DPP_ADD(0x114) DPP_ADD(0x118)             \
        DPP_ADD(0x142) DPP_ADD(0x143)                                           \
        if ((t & 63) == 63) wv[t >> 6] = ps;                                    \
    }

#define GAIN(C0) ((wid < 2) ? 1.0f + tanhf(wv[4 * wid] + wv[4 * wid + 1]        \
                   + wv[4 * wid + 2] + wv[4 * wid + 3] + bias[(C0) + wid]) : 0.f)

#define PASS_READ(VV)                                                           \
    _Pragma("unroll") for (int r = 0; r < 8; ++r) VV[r] = zb[rb + 544 * r];
#define PASS0_WRITE(VV)                                                         \
    { int wb_ = 8 * t + (t >> 1);                                               \
      _Pragma("unroll") for (int r = 0; r < 8; ++r) zb[wb_ + r] = VV[PERM8(r)]; }
#define PASS1_WRITE(VV)                                                         \
    { int wb_ = 64 * (t >> 3) + (t & 7);                                        \
      int B0_ = wb_ + (wb_ >> 4);                                               \
      int B1_ = (wb_ + 8) + ((wb_ + 8) >> 4);                                   \
      _Pragma("unroll") for (int s = 0; s < 4; ++s) {                           \
          zb[B0_ + 17 * s] = VV[PERM8(2 * s)];                                  \
          zb[B1_ + 17 * s] = VV[PERM8(2 * s + 1)]; } }
#define PASS2_WRITE(VV)                                                         \
    { int wb_ = 512 * (t >> 6) + (t & 63);                                      \
      int B2_ = wb_ + (wb_ >> 4);                                               \
      _Pragma("unroll") for (int r = 0; r < 8; ++r) zb[B2_ + 68 * r] = VV[PERM8(r)]; }
#define PASS3_INPLACE(VV)                                                       \
    { v2f w1_ = cmul(T1[t >> 6], T2[t & 63]);                                   \
      PASS_READ(VV)                                                             \
      twiddle7w(VV, w1_);                                                       \
      dft8(VV);                                                                 \
      _Pragma("unroll") for (int r = 0; r < 8; ++r) zb[rb + 544 * r] = VV[PERM8(r)]; \
      if (t == 0) zb[4352] = VV[0]; }

#define TOPK()                                                                  \
    if (wid < 4) {                                                              \
        int row_ = wid >> 1, hf_ = wid & 1;                                     \
        int kb_ = (hf_ << 10) + lane;                                           \
        int b1_ = PD(kb_), b2_ = PD(4096 - kb_);                                \
        float amp_[16]; float lv_ = -1.f; int lm_ = 0;                          \
        _Pragma("unroll")                                                       \
        for (int m = 0; m < 16; ++m) {                                          \
            v2f z_ = zb[b1_ + 68 * m], y_ = zb[b2_ - 68 * m];                   \
            v2f X_ = row_ ? unt1(z_, y_) : unt0(z_, y_);                        \
            float a_ = fmaf(X_.x, X_.x, X_.y * X_.y);                           \
            amp_[m] = a_;                                                       \
            if (a_ > lv_) { lv_ = a_; lm_ = m; }                                \
        }                                                                       \
        for (int it = 0; it < KK; ++it) {                                       \
            float bv = lv_; int bb = kb_ + (lm_ << 6);                          \
            DPP_STEP(0x111) DPP_STEP(0x112) DPP_STEP(0x114)                     \
            DPP_STEP(0x118) DPP_STEP(0x142) DPP_STEP(0x143)                     \
            float vw_ = __int_as_float(__builtin_amdgcn_readlane(__float_as_int(bv), 63)); \
            int   wn_ = __builtin_amdgcn_readlane(bb, 63);                      \
            if (lane == 0) { candV[row_][(hf_ << 3) + it] = vw_;                \
                             candB[row_][(hf_ << 3) + it] = wn_; }              \
            if ((wn_ & 63) == lane) {                                           \
                int m0_ = ((wn_ - (hf_ << 10)) >> 6);                           \
                lv_ = -1.f; lm_ = 0;                                            \
                _Pragma("unroll")                                               \
                for (int m = 0; m < 16; ++m) {                                  \
                    float a_ = (m == m0_) ? -1.f : amp_[m];                     \
                    amp_[m] = a_;                                               \
                    if (a_ > lv_) { lv_ = a_; lm_ = m; }                        \
                }                                                               \
            }                                                                   \
        }                                                                       \
    }

#define MERGE(G)                                                                \
    if (wid < 2 && lane < 17) {                                                 \
        int row_ = wid;                                                         \
        v2f z2_ = zb[PD(2048)];                                                 \
        float xn_ = 2.f * (row_ ? z2_.y : z2_.x);                               \
        float a2_ = xn_ * xn_;                                                  \
        float myv_; int myb_, rk_;                                              \
        if (lane < 16) {                                                        \
            myv_ = candV[row_][lane]; myb_ = candB[row_][lane];                 \
            rk_ = lane & 7;                                                     \
            int ob_ = (lane < 8) ? 8 : 0;                                       \
            _Pragma("unroll")                                                   \
            for (int j = 0; j < 8; ++j) {                                       \
                float ov_ = candV[row_][ob_ + j]; int on_ = candB[row_][ob_ + j]; \
                if (ov_ > myv_ || (ov_ == myv_ && on_ < myb_)) rk_++;           \
            }                                                                   \
            if (a2_ > myv_) rk_++;                                              \
        } else {                                                                \
            myv_ = a2_; myb_ = 2048; rk_ = 0;                                   \
            _Pragma("unroll")                                                   \
            for (int j = 0; j < 16; ++j)                                        \
                if (candV[row_][j] >= myv_) rk_++;                              \
        }                                                                       \
        if (rk_ < KK) {                                                         \
            v2f z_ = zb[PD(myb_)];                                              \
            v2f y_ = zb[PD(4096 - myb_)];                                       \
            v2f X_;                                                             \
            if (row_ == 0) X_ = (v2f){0.5f * (z_.x + y_.x), 0.5f * (z_.y - y_.y)}; \
            else           X_ = (v2f){0.5f * (z_.y + y_.y), 0.5f * (y_.x - z_.x)}; \
            bool ed_ = (myb_ == 0) || (myb_ == 2048);                           \
            float wg_ = (ed_ ? 1.f : 2.f) * (G) * (1.0f / 4096.0f);             \
            selF[row_][rk_] = myb_;                                             \
            selAB[row_][rk_] = (v2f){wg_ * X_.x, ed_ ? 0.f : wg_ * X_.y};       \
        }                                                                       \
    }

// One block per TWO row-pairs (A then B), software-pipelined: B's global
// loads issue during A's merge; inverse-A init/run interleave with B's
// pass-1/pass-2 segments to fill LDS-latency stalls with independent work.
__global__ __launch_bounds__(THREADS, 8)
void fft4_topk_k(const float* __restrict__ x, const float* __restrict__ te,
                 const float* __restrict__ W, const float* __restrict__ bias,
                 float* __restrict__ out) {
    __shared__ v2f zb[4353];
    __shared__ float wv[8];
    __shared__ float candV[2][16];
    __shared__ int   candB[2][16];
    __shared__ v2f  selAB[2][KK];
    __shared__ int  selF[2][KK];
    __shared__ v2f  T1[64], T2[64];

    int t = threadIdx.x;
    int wid = t >> 6, lane = t & 63;
    int mh = t >> 8, u = t & 255;
    int rb = t + (t >> 4);                 // PD(t + 512r) = rb + 544r

    int pA = blockIdx.x << 1;              // pairs A = 2blk, B = 2blk+1
    int b = pA >> 6;
    int c0A = (pA & 63) << 1;
    int c0B = c0A + 2;
    int row0A = (b << 7) + c0A;
    int row0B = row0A + 2;

    // ---------------- PAIR A: load + dot + LUTs ----------------
    const float* xA0 = x + (size_t)row0A * LL;
    const float* xA1 = xA0 + LL;
    v2f v[8];
#pragma unroll
    for (int r = 0; r < 8; ++r) { v[r].x = xA0[t + 512 * r]; v[r].y = xA1[t + 512 * r]; }
    MOD_DOT(c0A)
    if (t < 64) {
        float a = (float)t * (1.0f / 64.0f);
        T1[t] = (v2f){cosr(a), sinr(a)};
    } else if (t < 128) {
        float a = (float)(t - 64) * (1.0f / 4096.0f);
        T2[t - 64] = (v2f){cosr(a), sinr(a)};
    }

    // ---- FFT A ----
    dft8(v);
    PASS0_WRITE(v)
    __syncthreads();
    float g = GAIN(c0A);                   // early: hides bias load + tanh chain
    { PASS_READ(v) twiddle7w(v, T1[t & 7]); dft8(v); }
    __syncthreads();
    PASS1_WRITE(v)
    __syncthreads();
    { PASS_READ(v) twiddle7w(v, cmul(T1[(t & 63) >> 3], T2[(t & 7) << 3])); dft8(v); }
    __syncthreads();
    PASS2_WRITE(v)
    __syncthreads();
    PASS3_INPLACE(v)
    __syncthreads();

    TOPK()
    __syncthreads();

    // ---- merge A segment: also prefetch B + dot B (independent work) ----
    const float* xB0 = x + (size_t)row0B * LL;
    const float* xB1 = xB0 + LL;
    v2f vB[8];
#pragma unroll
    for (int r = 0; r < 8; ++r) { vB[r].x = xB0[t + 512 * r]; vB[r].y = xB1[t + 512 * r]; }
    MERGE(g)
    MOD_DOT(c0B)                           // wv dead for A (gain in register)
    __syncthreads();

    // ---------------- PAIR B FFT with inverse-A interleaved ----------------
    dft8(vB);
    PASS0_WRITE(vB)
    __syncthreads();
    g = GAIN(c0B);
    // pass 1 B + inverse-A init (independent: fills ds_read latency)
    { PASS_READ(vB) twiddle7w(vB, T1[t & 7]); dft8(vB); }
    v2f rcA[4], rpA[4], tcA[4], sgA[4];
    inv_init(rcA, rpA, tcA, sgA, &selF[mh][0], &selAB[mh][0], T1, T2, u);
    __syncthreads();
    PASS1_WRITE(vB)
    __syncthreads();
    // pass 2 B + inverse-A run (stores of A overlap B compute)
    { PASS_READ(vB) twiddle7w(vB, cmul(T1[(t & 63) >> 3], T2[(t & 7) << 3])); dft8(vB); }
    inv_run(rcA, rpA, tcA, sgA, out + (size_t)(row0A + mh) * LL, u);
    __syncthreads();
    PASS2_WRITE(vB)
    __syncthreads();
    PASS3_INPLACE(vB)
    __syncthreads();

    TOPK()
    __syncthreads();
    MERGE(g)
    __syncthreads();

    // ---- inverse B (tail) ----
    v2f rcB[4], rpB[4], tcB[4], sgB[4];
    inv_init(rcB, rpB, tcB, sgB, &selF[mh][0], &selAB[mh][0], T1, T2, u);
    inv_run(rcB, rpB, tcB, sgB, out + (size_t)(row0B + mh) * LL, u);
}

extern "C" void kernel_launch(void* const* d_in, const int* in_sizes, int n_in,
                              void* d_out, int out_size, void* d_ws, size_t ws_size,
                              hipStream_t stream) {
    const float* x    = (const float*)d_in[0];
    const float* te   = (const float*)d_in[1];
    const float* W    = (const float*)d_in[2];
    const float* bias = (const float*)d_in[3];
    float* out = (float*)d_out;
    fft4_topk_k<<<1024, THREADS, 0, stream>>>(x, te, W, bias, out);
}

// Round 18
// 44.520 us; speedup vs baseline: 1.1794x; 1.1794x over previous
//
#include <hip/hip_runtime.h>

#define LL 4096
#define THREADS 512
#define KK 8

typedef float v2f __attribute__((ext_vector_type(2)));

// Pad-1-per-16 layout: elem i lives at i + (i>>4). Uniform 4 lanes/bank-pair
// (b64 minimum) for every access pattern here; all FFT pass accesses fold to
// base + compile-time ds-offset immediates.
#define PD(i) ((i) + ((i) >> 4))
// dft8: X[k0+4*k1] sits in slot 2*k0+k1 -> slot holding X[r]:
#define PERM8(r) ((((r) & 3) << 1) | ((r) >> 2))

// HW trig, input in REVOLUTIONS: sinr(x)=sin(2*pi*x). All args are exact
// m/2^k in [0,1), so no range-reduction error.
__device__ __forceinline__ float sinr(float x) {
    float r; asm("v_sin_f32 %0, %1" : "=v"(r) : "v"(x)); return r;
}
__device__ __forceinline__ float cosr(float x) {
    float r; asm("v_cos_f32 %0, %1" : "=v"(r) : "v"(x)); return r;
}

// ---- VOP3P packed-f32 complex primitives ----
__device__ __forceinline__ v2f padd(v2f a, v2f b) {
    v2f d; asm("v_pk_add_f32 %0, %1, %2" : "=v"(d) : "v"(a), "v"(b)); return d;
}
__device__ __forceinline__ v2f psub(v2f a, v2f b) {
    v2f d; asm("v_pk_add_f32 %0, %1, %2 neg_lo:[0,1] neg_hi:[0,1]" : "=v"(d) : "v"(a), "v"(b)); return d;
}
__device__ __forceinline__ v2f pmul(v2f a, v2f b) {
    v2f d; asm("v_pk_mul_f32 %0, %1, %2" : "=v"(d) : "v"(a), "v"(b)); return d;
}
// a + (-i*b) = (a.x + b.y, a.y - b.x)
__device__ __forceinline__ v2f addmi(v2f a, v2f b) {
    v2f d; asm("v_pk_add_f32 %0, %1, %2 op_sel:[0,1] op_sel_hi:[1,0] neg_hi:[0,1]" : "=v"(d) : "v"(a), "v"(b)); return d;
}
// a - (-i*b) = (a.x - b.y, a.y + b.x)
__device__ __forceinline__ v2f submi(v2f a, v2f b) {
    v2f d; asm("v_pk_add_f32 %0, %1, %2 op_sel:[0,1] op_sel_hi:[1,0] neg_lo:[0,1]" : "=v"(d) : "v"(a), "v"(b)); return d;
}
// -i*a = (a.y, -a.x)
__device__ __forceinline__ v2f negi(v2f a) {
    v2f d; asm("v_pk_add_f32 %0, %1, 0 op_sel:[1,0] op_sel_hi:[0,0] neg_hi:[1,0]" : "=v"(d) : "v"(a)); return d;
}
__device__ __forceinline__ v2f pfma(v2f a, v2f b, v2f c) {
    v2f d; asm("v_pk_fma_f32 %0, %1, %2, %3" : "=v"(d) : "v"(a), "v"(b), "v"(c)); return d;
}
__device__ __forceinline__ v2f pfms(v2f a, v2f b, v2f c) {
    v2f d; asm("v_pk_fma_f32 %0, %1, %2, %3 neg_lo:[0,0,1] neg_hi:[0,0,1]" : "=v"(d) : "v"(a), "v"(b), "v"(c)); return d;
}
// complex multiply (a.x+i a.y)(b.x+i b.y): 2 instructions
__device__ __forceinline__ v2f cmul(v2f a, v2f b) {
    v2f t, d;
    asm("v_pk_mul_f32 %0, %1, %2 op_sel:[0,0] op_sel_hi:[0,1]" : "=v"(t) : "v"(a), "v"(b));
    asm("v_pk_fma_f32 %0, %1, %2, %3 op_sel:[1,1,0] op_sel_hi:[1,0,1] neg_lo:[1,0,0]"
        : "=v"(d) : "v"(a), "v"(b), "v"(t));
    return d;
}
// twiddle apply: z * (w.x - i*w.y): 2 instructions
__device__ __forceinline__ v2f cmulw(v2f z, v2f w) {
    v2f t, d;
    asm("v_pk_mul_f32 %0, %1, %2 op_sel:[0,0] op_sel_hi:[1,0]" : "=v"(t) : "v"(z), "v"(w));
    asm("v_pk_fma_f32 %0, %1, %2, %3 op_sel:[1,1,0] op_sel_hi:[0,1,1] neg_hi:[1,0,0]"
        : "=v"(d) : "v"(z), "v"(w), "v"(t));
    return d;
}
// untangle row0: (z.x+y.x, z.y-y.y); row1: (z.y+y.y, y.x-z.x)
__device__ __forceinline__ v2f unt0(v2f z, v2f y) {
    v2f d; asm("v_pk_add_f32 %0, %1, %2 neg_hi:[0,1]" : "=v"(d) : "v"(z), "v"(y)); return d;
}
__device__ __forceinline__ v2f unt1(v2f z, v2f y) {
    v2f d; asm("v_pk_add_f32 %0, %1, %2 op_sel:[1,1] op_sel_hi:[0,0] neg_hi:[1,0]" : "=v"(d) : "v"(z), "v"(y)); return d;
}

// forward 4-point DFT (w4 = -i), in place: 8 pk instructions
__device__ __forceinline__ void dft4(v2f& a, v2f& b, v2f& c, v2f& d) {
    v2f t0 = padd(a, c), t1 = psub(a, c);
    v2f t2 = padd(b, d), t3 = psub(b, d);
    a = padd(t0, t2); c = psub(t0, t2);
    b = addmi(t1, t3); d = submi(t1, t3);
}

// forward 8-point DFT; output permuted per PERM8
__device__ __forceinline__ void dft8(v2f* v) {
    dft4(v[0], v[2], v[4], v[6]);
    dft4(v[1], v[3], v[5], v[7]);
    const float C2 = 0.70710678118654752f;
    v[3] = cmulw(v[3], (v2f){C2, C2});
    v[5] = negi(v[5]);
    v[7] = cmulw(v[7], (v2f){-C2, C2});
#pragma unroll
    for (int k0 = 0; k0 < 4; ++k0) {
        v2f a = v[2 * k0], b = v[2 * k0 + 1];
        v[2 * k0]     = padd(a, b);
        v[2 * k0 + 1] = psub(a, b);
    }
}

// apply twiddles w^r (r=1..7) from given w1, tree-structured powers (depth 3)
__device__ __forceinline__ void twiddle7w(v2f* v, v2f w1) {
    v2f w2 = cmul(w1, w1);
    v2f w3 = cmul(w2, w1);
    v2f w4 = cmul(w2, w2);
    v2f w5 = cmul(w3, w2);
    v2f w6 = cmul(w3, w3);
    v2f w7 = cmul(w4, w3);
    v[1] = cmulw(v[1], w1);
    v[2] = cmulw(v[2], w2);
    v[3] = cmulw(v[3], w3);
    v[4] = cmulw(v[4], w4);
    v[5] = cmulw(v[5], w5);
    v[6] = cmulw(v[6], w6);
    v[7] = cmulw(v[7], w7);
}

// DPP argmax step: combine (bv,bb) with value shifted in by CTRL (self-keep).
#define DPP_STEP(CTRL)                                                          \
  {                                                                             \
    int vs_ = __builtin_amdgcn_update_dpp(__float_as_int(bv), __float_as_int(bv), \
                                          CTRL, 0xf, 0xf, false);               \
    int bs_ = __builtin_amdgcn_update_dpp(bb, bb, CTRL, 0xf, 0xf, false);       \
    float vf_ = __int_as_float(vs_);                                            \
    bool tk_ = (vf_ > bv) || (vf_ == bv && bs_ < bb);                           \
    bv = tk_ ? vf_ : bv; bb = tk_ ? bs_ : bb;                                   \
  }
// DPP sum-reduce step (invalid lanes contribute 0) -> lane 63 holds total
#define DPP_ADD(CTRL)                                                           \
  ps += __int_as_float(__builtin_amdgcn_update_dpp(0, __float_as_int(ps),       \
                                                   CTRL, 0xf, 0xf, true));

// One block per ROW PAIR: z = x0 + i*x1 (gain folded into selAB post-FFT),
// 4096-pt FFT (radix-8 x 4, LUT twiddle bases), 4-wave top-8 (DPP argmax) +
// 17-lane merge-path, packed-Chebyshev inverse with LUT-factored trig init.
// Output stores are nontemporal (write-once data; keeps x resident in L2/L3).
__global__ __launch_bounds__(THREADS, 8)
void fft2_topk_k(const float* __restrict__ x, const float* __restrict__ te,
                 const float* __restrict__ W, const float* __restrict__ bias,
                 float* __restrict__ out) {
    __shared__ v2f zb[4353];               // PD(4095)=4350; [4352] = dup of Z[0]
    __shared__ float wv[8];
    __shared__ float candV[2][16];         // [row][half*8+i], halves sorted desc
    __shared__ int   candB[2][16];
    __shared__ v2f  selAB[2][KK];          // (A, B) with gain folded in
    __shared__ int  selF[2][KK];
    __shared__ v2f  T1[64], T2[64];        // e^{i*h/64}, e^{i*l/4096}

    int t = threadIdx.x;
    int pair = blockIdx.x;
    int b = pair >> 6;
    int c0 = (pair & 63) << 1;
    int row0 = (b << 7) + c0;

    // issue all 16 global x-loads FIRST: HBM latency hides under dot + LUTs
    const float* xp0 = x + (size_t)row0 * LL;
    const float* xp1 = xp0 + LL;
    v2f v[8];
#pragma unroll
    for (int r = 0; r < 8; ++r) { v[r].x = xp0[t + 512 * r]; v[r].y = xp1[t + 512 * r]; }

    // modulation dots: threads<256 -> row0, >=256 -> row1 (DPP sum reduce)
    {
        int mh = t >> 8, tt = t & 255;
        const float* tp = te + b * 512;
        const float* wp = W + (c0 + mh) * 512;
        float ps = tp[tt] * wp[tt] + tp[tt + 256] * wp[tt + 256];
        DPP_ADD(0x111) DPP_ADD(0x112) DPP_ADD(0x114) DPP_ADD(0x118)
        DPP_ADD(0x142) DPP_ADD(0x143)
        if ((t & 63) == 63) wv[t >> 6] = ps;
    }
    // build trig LUTs (ready before the pass-0 barrier; used from pass 1 on)
    if (t < 64) {
        float a = (float)t * (1.0f / 64.0f);
        T1[t] = (v2f){cosr(a), sinr(a)};
    } else if (t < 128) {
        float a = (float)(t - 64) * (1.0f / 4096.0f);
        T2[t - 64] = (v2f){cosr(a), sinr(a)};
    }

    // ---- pass 0 (Ns=1): elem 8t+r -> PD = 8t + (t>>1) + r ----
    dft8(v);
    {
        int wb = 8 * t + (t >> 1);
#pragma unroll
        for (int r = 0; r < 8; ++r) zb[wb + r] = v[PERM8(r)];
    }
    __syncthreads();

    int rb = t + (t >> 4);                 // PD(t + 512r) = rb + 544r

    // ---- pass 1 (Ns=8): w1 = e^{i(t&7)/64} = T1[t&7] (LUT, no trans) ----
    {
        v2f w1 = T1[t & 7];
#pragma unroll
        for (int r = 0; r < 8; ++r) v[r] = zb[rb + 544 * r];
        twiddle7w(v, w1);
    }
    dft8(v);
    __syncthreads();
    {
        int wb = 64 * (t >> 3) + (t & 7);
        int B0 = wb + (wb >> 4);
        int B1 = (wb + 8) + ((wb + 8) >> 4);
#pragma unroll
        for (int s = 0; s < 4; ++s) {
            zb[B0 + 17 * s] = v[PERM8(2 * s)];
            zb[B1 + 17 * s] = v[PERM8(2 * s + 1)];
        }
    }
    __syncthreads();

    // ---- pass 2 (Ns=64): w1 = e^{i(t&63)/512} = T1[(t&63)>>3]*T2[(t&7)<<3] ----
    {
        v2f w1 = cmul(T1[(t & 63) >> 3], T2[(t & 7) << 3]);
#pragma unroll
        for (int r = 0; r < 8; ++r) v[r] = zb[rb + 544 * r];
        twiddle7w(v, w1);
    }
    dft8(v);
    __syncthreads();
    {
        int wb = 512 * (t >> 6) + (t & 63);
        int B2 = wb + (wb >> 4);
#pragma unroll
        for (int r = 0; r < 8; ++r) zb[B2 + 68 * r] = v[PERM8(r)];
    }
    __syncthreads();

    // ---- pass 3 (Ns=512): w1 = e^{i*t/4096} = T1[t>>6]*T2[t&63]; in-place ----
    {
        v2f w1 = cmul(T1[t >> 6], T2[t & 63]);
#pragma unroll
        for (int r = 0; r < 8; ++r) v[r] = zb[rb + 544 * r];
        twiddle7w(v, w1);
    }
    dft8(v);
#pragma unroll
    for (int r = 0; r < 8; ++r) zb[rb + 544 * r] = v[PERM8(r)];
    if (t == 0) zb[4352] = v[0];           // duplicate Z[0] at PD(4096)
    __syncthreads();

    int wid = t >> 6, lane = t & 63;

    // ---- top-8: 4 waves (2/row), 16 bins/lane, DPP argmax, no syncs.
    // amp on UNSCALED spectra (gain>0, ranking-invariant). Affine addressing.
    if (wid < 4) {
        int row = wid >> 1, hf = wid & 1;
        int kb = (hf << 10) + lane;        // bins kb + 64m, m=0..15
        int base1 = PD(kb);
        int base2 = PD(4096 - kb);
        float amp[16];
        float lv = -1.f; int lm = 0;
#pragma unroll
        for (int m = 0; m < 16; ++m) {
            v2f z = zb[base1 + 68 * m];
            v2f y = zb[base2 - 68 * m];
            v2f X = row ? unt1(z, y) : unt0(z, y);
            float a = fmaf(X.x, X.x, X.y * X.y);
            amp[m] = a;
            if (a > lv) { lv = a; lm = m; }   // ascending m => lower bin on tie
        }
        for (int it = 0; it < KK; ++it) {
            float bv = lv; int bb = kb + (lm << 6);
            DPP_STEP(0x111)                 // row_shr:1
            DPP_STEP(0x112)                 // row_shr:2
            DPP_STEP(0x114)                 // row_shr:4
            DPP_STEP(0x118)                 // row_shr:8
            DPP_STEP(0x142)                 // row_bcast:15
            DPP_STEP(0x143)                 // row_bcast:31  -> result in lane 63
            float vwin = __int_as_float(__builtin_amdgcn_readlane(__float_as_int(bv), 63));
            int   wbin = __builtin_amdgcn_readlane(bb, 63);
            if (lane == 0) { candV[row][(hf << 3) + it] = vwin; candB[row][(hf << 3) + it] = wbin; }
            if ((wbin & 63) == lane) {         // owner removes + rescans (masked)
                int m0 = ((wbin - (hf << 10)) >> 6);
                lv = -1.f; lm = 0;
#pragma unroll
                for (int m = 0; m < 16; ++m) {
                    float a = (m == m0) ? -1.f : amp[m];
                    amp[m] = a;
                    if (a > lv) { lv = a; lm = m; }
                }
            }
        }
    }
    __syncthreads();

    // ---- merge-path combine: wave0 -> row0, wave1 -> row1; 17 candidates.
    // Gain g = 1+tanh(scale) computed HERE only (34 lanes) and folded into AB.
    if (wid < 2 && lane < 17) {
        int row = wid;
        float g = 1.0f + tanhf(wv[4 * row] + wv[4 * row + 1] + wv[4 * row + 2]
                               + wv[4 * row + 3] + bias[c0 + row]);
        v2f z2 = zb[PD(2048)];
        float xn = 2.f * (row ? z2.y : z2.x);   // matches 2X amp scaling
        float a2048 = xn * xn;
        float myv; int myb, rank;
        if (lane < 16) {
            myv = candV[row][lane]; myb = candB[row][lane];
            rank = lane & 7;
            int ob = (lane < 8) ? 8 : 0;        // compare vs the other list
#pragma unroll
            for (int j = 0; j < 8; ++j) {
                float ov = candV[row][ob + j]; int obn = candB[row][ob + j];
                if (ov > myv || (ov == myv && obn < myb)) rank++;
            }
            if (a2048 > myv) rank++;            // 2048 is highest bin: strict >
        } else {
            myv = a2048; myb = 2048; rank = 0;
#pragma unroll
            for (int j = 0; j < 16; ++j)
                if (candV[row][j] >= myv) rank++;   // ties beat bin 2048
        }
        if (rank < KK) {                        // top-8 member: record
            v2f z = zb[PD(myb)];
            v2f y = zb[PD(4096 - myb)];         // myb=0 -> dup slot 4352
            v2f X;
            if (row == 0) X = (v2f){0.5f * (z.x + y.x), 0.5f * (z.y - y.y)};
            else          X = (v2f){0.5f * (z.y + y.y), 0.5f * (y.x - z.x)};
            bool edge = (myb == 0) || (myb == 2048);
            float wgt = (edge ? 1.f : 2.f) * g * (1.0f / 4096.0f);
            selF[row][rank] = myb;
            selAB[row][rank] = (v2f){wgt * X.x, edge ? 0.f : wgt * X.y};
        }
    }
    __syncthreads();

    // ---- sparse inverse via packed Chebyshev recurrence ----
    // r_k(q) = Re[(A+iB)e^{i*2pi*f*(u+256q)/L}]:
    // r(q+1) = 2cos(2pi*f*256/L)*r(q) - r(q-1). Two freqs per v2f.
    // init trig via factored LUT: e^{i*m/4096} = T1[m>>6] * T2[m&63].
    {
        int mh = t >> 8, u = t & 255;
        v2f rc[4], rp[4], tcv[4], sgv[4];
#pragma unroll
        for (int j = 0; j < 4; ++j) {
            int f0 = selF[mh][2 * j], f1 = selF[mh][2 * j + 1];
            v2f A0 = selAB[mh][2 * j], A1 = selAB[mh][2 * j + 1];
            int m0 = (f0 * u) & 4095, m1 = (f1 * u) & 4095;
            v2f e0 = cmul(T1[m0 >> 6], T2[m0 & 63]);
            v2f e1 = cmul(T1[m1 >> 6], T2[m1 & 63]);
            v2f w0 = cmul(A0, e0);                  // (Re w(u), Im w(u))
            v2f w1 = cmul(A1, e1);
            v2f s0 = T1[(f0 & 15) << 2];            // step e^{i*(f&15)/16}
            v2f s1 = T1[(f1 & 15) << 2];
            rc[j] = (v2f){w0.x, w1.x};
            // r(-1) = Re[w(u) e^{-i*step}] = Re*cos + Im*sin
            rp[j] = (v2f){w0.x * s0.x + w0.y * s0.y, w1.x * s1.x + w1.y * s1.y};
            tcv[j] = (v2f){s0.x + s0.x, s1.x + s1.x};
            sgv[j] = (v2f){(f0 & 1) ? -1.f : 1.f, (f1 & 1) ? -1.f : 1.f};
        }
        float* op = out + (size_t)(row0 + mh) * LL;
#pragma unroll
        for (int q2 = 0; q2 < 8; ++q2) {
            v2f accv = padd(padd(rc[0], rc[1]), padd(rc[2], rc[3]));
            v2f acdv = pfma(rc[0], sgv[0],
                       pfma(rc[1], sgv[1],
                       pfma(rc[2], sgv[2], pmul(rc[3], sgv[3]))));
            __builtin_nontemporal_store(accv.x + accv.y, &op[u + (q2 << 8)]);
            __builtin_nontemporal_store(acdv.x + acdv.y, &op[u + (q2 << 8) + 2048]);
#pragma unroll
            for (int j = 0; j < 4; ++j) {
                v2f rn = pfms(tcv[j], rc[j], rp[j]);
                rp[j] = rc[j];
                rc[j] = rn;
            }
        }
    }
}

extern "C" void kernel_launch(void* const* d_in, const int* in_sizes, int n_in,
                              void* d_out, int out_size, void* d_ws, size_t ws_size,
                              hipStream_t stream) {
    const float* x    = (const float*)d_in[0];
    const float* te   = (const float*)d_in[1];
    const float* W    = (const float*)d_in[2];
    const float* bias = (const float*)d_in[3];
    float* out = (float*)d_out;
    fft2_topk_k<<<2048, THREADS, 0, stream>>>(x, te, W, bias, out);
}